// Round 8
// baseline (138.025 us; speedup 1.0000x reference)
//
#include <hip/hip_runtime.h>
#include <math.h>

// NMSLoss4: B=8, N=2048, G=64. Key-sorted (desc) space: every killer of e
// has index < e, so ONE ordered Gauss-Seidel sweep (single wave, 32 word
// steps, intra-word ballot iteration) gives the exact sequential-NMS fixed
// point. Round 7: bitonic sort (66 barrier phases, 53us) replaced by
// rank-scatter (zero phases); sweep edge loops unrolled to fixed CAP trips
// so LDS reads issue in parallel.

#define B_IMG 8
#define NN 2048
#define GG 64
#define MIN_H 50.0f
#define EPSF 1e-6f
#define CAP 12
#define OVF_MAX 2048
#define TILE 256
#define NTILE 8
#define NPAIRT 36            // triangular 256x256 tile pairs
#define CSLICE 64

// per-image ws layout (bytes)
#define OFF_SBOX 0           // float4[2048] sorted boxes      32768
#define OFF_GTPI 32768       // f32[2048]                       8192
#define OFF_PULL 40960       // f32[2048]                       8192
#define OFF_AGTI 49152       // s8[2048]                        2048
#define OFF_CNT  51200       // u32[2048]                       8192
#define OFF_NPOS 59392       // u32 (+pad)
#define OFF_OVFC 59648       // u32 (+pad)
#define OFF_OVF  59904       // u32[2048]                       8192
#define OFF_INL  68096       // u16[2048*12]                   49152
#define IMG_STRIDE 117248

__device__ __forceinline__ float iou_pair(
    float ax1, float ay1, float ax2, float ay2,
    float bx1, float by1, float bx2, float by2) {
  float area_a = (ax2 - ax1) * (ay2 - ay1);
  float area_b = (bx2 - bx1) * (by2 - by1);
  float lx = fmaxf(ax1, bx1), ly = fmaxf(ay1, by1);
  float rx = fminf(ax2, bx2), ry = fminf(ay2, by2);
  float w = fmaxf(rx - lx, 0.0f), h = fmaxf(ry - ly, 0.0f);
  float inter = w * h;
  return inter / (area_a + area_b - inter + 1e-10f);
}

// ------------- kernel 1: rank-scatter sort (desc) + per-box prep ------------
__global__ __launch_bounds__(256) void k_rank(
    const int* __restrict__ agti_all,
    const float* __restrict__ gtb_all,
    const float* __restrict__ prop_all,
    unsigned char* __restrict__ ws,
    float* __restrict__ out) {
  const int b = blockIdx.x >> 3, chunk = blockIdx.x & 7;
  const int tid = threadIdx.x;
  const int e = (chunk << 8) | tid;          // original index this thread owns
  const int* agti = agti_all + b * NN;
  const float* prop = prop_all + (size_t)b * NN * 5;
  unsigned char* W = ws + (size_t)b * IMG_STRIDE;

  __shared__ unsigned long long keys[NN];    // 16384 B
  __shared__ float sgt[GG * 4];

  if (blockIdx.x == 0 && tid == 0) { out[0] = 0.f; out[1] = 0.f; }
  if (chunk == 0 && tid == 0) *(unsigned*)(W + OFF_OVFC) = 0u;
  sgt[tid] = gtb_all[b * GG * 4 + tid];
  for (int s = tid; s < NN; s += 256) {
    int a = agti[s];
    float sc = prop[s * 5 + 4];
    // higher key = earlier selection; ties -> lower orig idx (jnp.argmax).
    keys[s] = (a >= 0)
        ? ((unsigned long long)__float_as_uint(sc) << 32) | (unsigned)(NN - 1 - s)
        : 0ull;
  }
  __syncthreads();

  const unsigned long long myk = keys[e];
  int rank = 0, npos = 0;
  #pragma unroll 4
  for (int f = 0; f < NN; ++f) {
    unsigned long long kf = keys[f];          // LDS broadcast
    rank += (kf > myk) ? 1 : 0;
    rank += (kf == myk && f < e) ? 1 : 0;     // stable among equal (zero) keys
    npos += (kf != 0ull) ? 1 : 0;
  }
  if (chunk == 0 && tid == 0) *(unsigned*)(W + OFF_NPOS) = (unsigned)npos;

  float4 bx = make_float4(0.f, 0.f, 0.f, 0.f);
  float gi = 0.f, pl = 0.f;
  int a = -1;
  if (myk != 0ull) {
    bx = make_float4(prop[e * 5 + 0], prop[e * 5 + 1],
                     prop[e * 5 + 2], prop[e * 5 + 3]);
    float sc = prop[e * 5 + 4];
    a = agti[e];
    gi = iou_pair(sgt[a * 4 + 0], sgt[a * 4 + 1], sgt[a * 4 + 2], sgt[a * 4 + 3],
                  bx.x, bx.y, bx.z, bx.w);
    pl = -logf(fminf(0.5f + fmaxf(gi, EPSF), 1.0f)) * sc;
  }
  ((float4*)(W + OFF_SBOX))[rank] = bx;
  ((float*)(W + OFF_GTPI))[rank] = gi;
  ((float*)(W + OFF_PULL))[rank] = pl;
  ((signed char*)(W + OFF_AGTI))[rank] = (signed char)a;
  ((unsigned*)(W + OFF_CNT))[rank] = 0u;
}

// ------------- kernel 2: tiled all-pairs (sorted) -> in-edge lists ----------
// killer is ALWAYS i (i<j in sorted space). Exact divide-free predicate:
// fl32(inter/denom) > 0.5f  <=>  (double)inter > (0.5+2^-25)*(double)denom
__global__ __launch_bounds__(256) void k_pairs(unsigned char* __restrict__ ws) {
  int bx = blockIdx.x;
  const int b = bx / (NPAIRT * 4);
  int rem = bx % (NPAIRT * 4);
  int p = rem >> 2;
  const int q = rem & 3;
  int r = 0;
  #pragma unroll
  for (int t = 0; t < NTILE; ++t) {
    int wdt = NTILE - t;
    if (p < wdt) { r = t; break; }
    p -= wdt;
  }
  const int c = r + p;
  const int tid = threadIdx.x;
  unsigned char* W = ws + (size_t)b * IMG_STRIDE;
  const float4* box = (const float4*)(W + OFF_SBOX);
  unsigned* cnt = (unsigned*)(W + OFF_CNT);
  unsigned short* inl = (unsigned short*)(W + OFF_INL);
  unsigned* ovfc = (unsigned*)(W + OFF_OVFC);
  unsigned* ovf = (unsigned*)(W + OFF_OVF);
  const int npos = (int)*(const unsigned*)(W + OFF_NPOS);

  const int jbase = c * TILE + q * CSLICE;
  if (jbase >= npos || r * TILE >= npos) return;   // uniform exits

  __shared__ float4 cbox[CSLICE];
  __shared__ float carea[CSLICE];

  if (tid < CSLICE) {
    float4 Bx = box[jbase + tid];
    cbox[tid] = Bx;
    carea[tid] = (Bx.z - Bx.x) * (Bx.w - Bx.y);
  }
  const int i = r * TILE + tid;
  const float4 A = box[i];
  const float area_a = (A.z - A.x) * (A.w - A.y);
  __syncthreads();

  const double THR = 0.5 + 0x1p-25;
  #pragma unroll 8
  for (int jj = 0; jj < CSLICE; ++jj) {
    float4 Bx = cbox[jj];
    float ab = carea[jj];
    float lx = fmaxf(A.x, Bx.x), ly = fmaxf(A.y, Bx.y);
    float rx = fminf(A.z, Bx.z), ry = fminf(A.w, Bx.w);
    float w = fmaxf(rx - lx, 0.0f), h = fmaxf(ry - ly, 0.0f);
    float inter = w * h;
    float denom = area_a + ab - inter + 1e-10f;   // ((aa+ab)-inter)+eps
    int j = jbase + jj;
    bool hit = ((double)inter > THR * (double)denom) && (j > i) && (j < npos);
    if (hit) {
      unsigned pos = atomicAdd(&cnt[j], 1u);
      if (pos < CAP) {
        inl[j * CAP + pos] = (unsigned short)i;
      } else {
        unsigned o = atomicAdd(ovfc, 1u);
        if (o < OVF_MAX) ovf[o] = ((unsigned)j << 16) | (unsigned)i;
      }
    }
  }
}

// ------------- kernel 3: single-sweep resolve + bookkeeping + final ---------
__global__ __launch_bounds__(512) void k_resolve(
    const float* __restrict__ gtb_all,
    unsigned char* __restrict__ ws,
    float* __restrict__ out) {
  const int b = blockIdx.x, tid = threadIdx.x;
  const int wave = tid >> 6, lane = tid & 63;
  unsigned char* W = ws + (size_t)b * IMG_STRIDE;
  const float4* sbox = (const float4*)(W + OFF_SBOX);
  const float* gtpi = (const float*)(W + OFF_GTPI);
  const float* pull = (const float*)(W + OFF_PULL);
  const signed char* ag8 = (const signed char*)(W + OFF_AGTI);
  const unsigned* cntg = (const unsigned*)(W + OFF_CNT);
  const int npos = (int)*(const unsigned*)(W + OFF_NPOS);

  __shared__ __align__(8) unsigned short inl_l[NN * CAP];  // 49152 B
  __shared__ unsigned char cnt8[NN];
  __shared__ unsigned long long selw[32];
  __shared__ unsigned l_ovf[OVF_MAX];                      // 8192 B
  __shared__ int minselg[GG], bestposg[GG];
  __shared__ int s_maxsel, s_hasrem;
  __shared__ float wtp[8];

  const unsigned ovfc_raw = *(const unsigned*)(W + OFF_OVFC);
  const int novf = (int)(ovfc_raw < OVF_MAX ? ovfc_raw : OVF_MAX);
  const bool ovflow = ovfc_raw > OVF_MAX;

  if (tid == 0) { s_maxsel = -1; s_hasrem = 0; }
  if (tid < GG) { minselg[tid] = NN; bestposg[tid] = NN; }
  {
    const unsigned long long* src = (const unsigned long long*)(W + OFF_INL);
    unsigned long long* dst = (unsigned long long*)inl_l;
    #pragma unroll
    for (int k = 0; k < 12; ++k) dst[tid + (k << 9)] = src[tid + (k << 9)];
  }
  for (int s = tid; s < NN; s += 512) {
    unsigned cc = cntg[s];
    cnt8[s] = (unsigned char)(cc > 255u ? 255u : cc);
  }
  for (int o = tid; o < novf; o += 512) l_ovf[o] = ((const unsigned*)(W + OFF_OVF))[o];
  __syncthreads();

  // ---- single ordered sweep (wave 0 only): exact sequential-NMS result ----
  if (wave == 0) {
    for (int w = 0; w < 32; ++w) {
      if ((w << 6) >= npos) { if (lane == 0) selw[w] = 0ull; continue; }
      const int e = (w << 6) | lane;
      const bool pos = e < npos;
      unsigned long long intra = 0ull;
      bool ckill = false;
      const int cfull = pos ? cnt8[e] : 0;
      const int ce = cfull < CAP ? cfull : CAP;
      // fixed-trip unroll: all LDS reads issue independently (one wait)
      #pragma unroll
      for (int kk = 0; kk < CAP; ++kk) {
        int idx = inl_l[e * CAP + kk];
        bool valid = kk < ce;
        bool intraw = idx >= (w << 6);
        unsigned long long selbit = (selw[idx >> 6] >> (idx & 63)) & 1ull;
        intra |= (valid && intraw) ? (1ull << (idx & 63)) : 0ull;
        ckill |= (valid && !intraw && selbit != 0ull);
      }
      if (novf && pos && cfull > CAP) {
        for (int o = 0; o < novf; ++o) {
          unsigned pk = l_ovf[o];
          if ((int)(pk >> 16) == e) {
            int idx = (int)(pk & 0xffffu);
            if (idx >= (w << 6)) intra |= 1ull << (idx & 63);
            else ckill |= ((selw[idx >> 6] >> (idx & 63)) & 1ull) != 0ull;
          }
        }
      }
      // ultra-rare exact fallback (overflow list itself overflowed)
      bool fb = ovflow && pos && cfull > CAP;
      if (__any(fb ? 1 : 0)) {
        float4 mb = sbox[e];
        if (fb) {
          ckill = false; intra = 0ull;
          for (int wp = 0; wp < w && !ckill; ++wp) {
            unsigned long long m = selw[wp];
            while (m && !ckill) {
              int bit = __ffsll((long long)m) - 1;
              m &= m - 1ull;
              float4 I = sbox[(wp << 6) | bit];
              if (iou_pair(I.x, I.y, I.z, I.w, mb.x, mb.y, mb.z, mb.w) > 0.5f)
                ckill = true;
            }
          }
        }
        for (int lp = 0; lp < 64; ++lp) {
          float bx1 = __shfl(mb.x, lp, 64), by1 = __shfl(mb.y, lp, 64);
          float bx2 = __shfl(mb.z, lp, 64), by2 = __shfl(mb.w, lp, 64);
          if (fb && lp < lane && ((w << 6) | lp) < npos) {
            if (iou_pair(bx1, by1, bx2, by2, mb.x, mb.y, mb.z, mb.w) > 0.5f)
              intra |= 1ull << lp;
          }
        }
      }
      const bool alive0 = pos && !ckill;
      bool alive = alive0;
      unsigned long long bal = __ballot(alive), prev;
      do {
        prev = bal;
        alive = alive0 && ((intra & bal) == 0ull);
        bal = __ballot(alive);
      } while (bal != prev);
      if (lane == 0) selw[w] = bal;
    }
  }
  __syncthreads();

  // ---- bookkeeping pass 1 ----
  float tp_part = 0.f;
  int maxsel_p = -1;
  #pragma unroll
  for (int k = 0; k < 4; ++k) {
    int e = tid + (k << 9);
    if (e < npos) {
      int g = ag8[e];
      atomicMin(&bestposg[g], e);
      bool sel = (selw[e >> 6] >> (e & 63)) & 1ull;
      if (sel) {
        atomicMin(&minselg[g], e);
        tp_part += pull[e];
        maxsel_p = e > maxsel_p ? e : maxsel_p;
      }
    }
  }
  #pragma unroll
  for (int off = 32; off; off >>= 1) {
    int o = __shfl_xor(maxsel_p, off, 64);
    maxsel_p = o > maxsel_p ? o : maxsel_p;
  }
  if (lane == 0) atomicMax(&s_maxsel, maxsel_p);
  __syncthreads();

  // ---- pass 2: first-of-g subtraction; has_rem for last selection ----
  const int idx_last = s_maxsel;
  #pragma unroll
  for (int k = 0; k < 4; ++k) {
    int e = tid + (k << 9);
    if (e >= npos) continue;
    bool sel = (selw[e >> 6] >> (e & 63)) & 1ull;
    if (sel) {
      if (e == minselg[ag8[e]]) tp_part -= pull[e];   // first of its g
    } else {
      // killed box: active at i_last's turn iff its ONLY selected killer is i_last
      bool other = false;
      int cfull = cnt8[e];
      int ce = cfull < CAP ? cfull : CAP;
      #pragma unroll
      for (int kk = 0; kk < CAP; ++kk) {
        int idx = inl_l[e * CAP + kk];
        bool valid = kk < ce;
        other |= valid && idx != idx_last &&
                 ((selw[idx >> 6] >> (idx & 63)) & 1ull) != 0ull;
      }
      if (!other && novf && cfull > CAP) {
        for (int o = 0; o < novf && !other; ++o) {
          unsigned pk = l_ovf[o];
          if ((int)(pk >> 16) == e) {
            int idx = (int)(pk & 0xffffu);
            if (idx != idx_last && ((selw[idx >> 6] >> (idx & 63)) & 1ull)) other = true;
          }
        }
      }
      if (!other && ovflow && cfull > CAP) {
        float4 mb = sbox[e];
        for (int wp = 0; wp <= ((e - 1) >> 6) && !other; ++wp) {
          unsigned long long m = selw[wp];
          while (m && !other) {
            int bit = __ffsll((long long)m) - 1;
            m &= m - 1ull;
            int idx = (wp << 6) | bit;
            if (idx < e && idx != idx_last) {
              float4 I = sbox[idx];
              if (iou_pair(I.x, I.y, I.z, I.w, mb.x, mb.y, mb.z, mb.w) > 0.5f)
                other = true;
            }
          }
        }
      }
      if (!other) s_hasrem = 1;
    }
  }
  #pragma unroll
  for (int off = 32; off; off >>= 1) tp_part += __shfl_xor(tp_part, off, 64);
  if (lane == 0) wtp[wave] = tp_part;
  __syncthreads();

  // ---- push + finalize (wave 0; lane == g) ----
  if (wave == 0) {
    float mypush = 0.f;
    int mycnt2 = 0;
    int bp = bestposg[lane];
    bool seen = minselg[lane] < NN;
    if (bp < NN) {
      float h = gtb_all[b * GG * 4 + lane * 4 + 3] - gtb_all[b * GG * 4 + lane * 4 + 1];
      if (h >= MIN_H && !seen) { mypush = 1.0f - gtpi[bp]; mycnt2 = 1; }
    }
    #pragma unroll
    for (int off = 32; off; off >>= 1) {
      mypush += __shfl_xor(mypush, off, 64);
      mycnt2 += __shfl_xor(mycnt2, off, 64);
    }
    if (lane == 0) {
      float tp = 0.f;
      #pragma unroll
      for (int w = 0; w < 8; ++w) tp += wtp[w];
      int total_sel = 0;
      for (int w = 0; w < 32; ++w) total_sel += __popcll(selw[w]);
      int distinct = 0;
      for (int g = 0; g < GG; ++g) distinct += (minselg[g] < NN) ? 1 : 0;
      int pc = total_sel - distinct;
      if (idx_last >= 0) {
        int gl = ag8[idx_last];
        // last selection's pull counts only if non-first-of-g AND has_rem
        if (idx_last != minselg[gl] && !s_hasrem) tp -= pull[idx_last];
      }
      float push_loss = 0.f, pull_loss = 0.f;
      if (npos > 1) {
        pull_loss = tp / ((float)pc + EPSF);
        push_loss = mypush / ((float)mycnt2 + EPSF);
      }
      atomicAdd(&out[0], push_loss * (1.0f / B_IMG));
      atomicAdd(&out[1], pull_loss * (1.0f / B_IMG));
    }
  }
}

extern "C" void kernel_launch(void* const* d_in, const int* in_sizes, int n_in,
                              void* d_out, int out_size, void* d_ws, size_t ws_size,
                              hipStream_t stream) {
  const int* agti = (const int*)d_in[1];
  const float* gtb = (const float*)d_in[2];
  const float* prop = (const float*)d_in[3];
  unsigned char* ws = (unsigned char*)d_ws;
  float* out = (float*)d_out;

  k_rank<<<B_IMG * 8, 256, 0, stream>>>(agti, gtb, prop, ws, out);
  k_pairs<<<B_IMG * NPAIRT * 4, 256, 0, stream>>>(ws);
  k_resolve<<<B_IMG, 512, 0, stream>>>(gtb, ws, out);
}

// Round 9
// 78.141 us; speedup vs baseline: 1.7664x; 1.7664x over previous
//
#include <hip/hip_runtime.h>
#include <math.h>

// NMSLoss4: B=8, N=2048, G=64. Key-sorted (desc) space: every killer of e
// has index < e, so ONE ordered Gauss-Seidel sweep (single wave, 32 word
// steps, intra-word ballot iteration) gives the exact sequential-NMS fixed
// point. Round 8: rank computed as 8x8 chunk partials across 512 blocks
// (0.7us broadcast loops, full occupancy) + separate scatter kernel;
// replaces the 77us latency-bound single-chunk rank loop.

#define B_IMG 8
#define NN 2048
#define GG 64
#define MIN_H 50.0f
#define EPSF 1e-6f
#define CAP 12
#define OVF_MAX 2048
#define TILE 256
#define NTILE 8
#define NPAIRT 36            // triangular 256x256 tile pairs
#define CSLICE 64

// per-image ws layout (bytes)
#define OFF_SBOX 0           // float4[2048] sorted boxes      32768
#define OFF_GTPI 32768       // f32[2048]                       8192
#define OFF_PULL 40960       // f32[2048]                       8192
#define OFF_AGTI 49152       // s8[2048]                        2048
#define OFF_CNT  51200       // u32[2048]                       8192
#define OFF_NPOSP 59392      // u32[8] per-chunk positive counts (+pad)
#define OFF_OVFC 59648       // u32 (+pad)
#define OFF_OVF  59904       // u32[2048]                       8192
#define OFF_INL  68096       // u16[2048*12]                   49152
// rankpart u16[8][2048] (32768 B) ALIASES OFF_INL: written by k_rank, read
// by k_scatter, both strictly before k_pairs writes inl (stream order).
#define OFF_RANKP OFF_INL
#define IMG_STRIDE 117248

__device__ __forceinline__ float iou_pair(
    float ax1, float ay1, float ax2, float ay2,
    float bx1, float by1, float bx2, float by2) {
  float area_a = (ax2 - ax1) * (ay2 - ay1);
  float area_b = (bx2 - bx1) * (by2 - by1);
  float lx = fmaxf(ax1, bx1), ly = fmaxf(ay1, by1);
  float rx = fminf(ax2, bx2), ry = fminf(ay2, by2);
  float w = fmaxf(rx - lx, 0.0f), h = fmaxf(ry - ly, 0.0f);
  float inter = w * h;
  return inter / (area_a + area_b - inter + 1e-10f);
}

__device__ __forceinline__ unsigned long long make_key(int a, float sc, int idx) {
  // higher key = earlier selection; ties -> lower orig idx (jnp.argmax).
  return (a >= 0)
      ? ((unsigned long long)__float_as_uint(sc) << 32) | (unsigned)(NN - 1 - idx)
      : 0ull;
}

// ------------- kernel 1: rank partials (8x8 chunk grid, 512 blocks) ---------
__global__ __launch_bounds__(256) void k_rank(
    const int* __restrict__ agti_all,
    const float* __restrict__ prop_all,
    unsigned char* __restrict__ ws) {
  const int bidx = blockIdx.x;
  const int b = bidx >> 6;
  const int ec = (bidx >> 3) & 7, fc = bidx & 7;
  const int tid = threadIdx.x;
  const int* agti = agti_all + b * NN;
  const float* prop = prop_all + (size_t)b * NN * 5;
  unsigned char* W = ws + (size_t)b * IMG_STRIDE;

  __shared__ unsigned long long fkeys[TILE];
  const int f0 = fc << 8;
  {
    const int f = f0 + tid;
    fkeys[tid] = make_key(agti[f], prop[f * 5 + 4], f);
  }
  const int e = (ec << 8) + tid;
  const unsigned long long myk = make_key(agti[e], prop[e * 5 + 4], e);
  __syncthreads();

  int rank = 0;
  #pragma unroll 16
  for (int ff = 0; ff < TILE; ++ff) {
    unsigned long long kf = fkeys[ff];       // LDS broadcast
    int fi = f0 + ff;
    // stable: ties (only zero keys) ordered by original index
    rank += (kf > myk || (kf == myk && fi < e)) ? 1 : 0;
  }
  ((unsigned short*)(W + OFF_RANKP))[(fc << 11) + e] = (unsigned short)rank;
}

// ------------- kernel 2: scatter to sorted slots + per-box prep -------------
__global__ __launch_bounds__(256) void k_scatter(
    const int* __restrict__ agti_all,
    const float* __restrict__ gtb_all,
    const float* __restrict__ prop_all,
    unsigned char* __restrict__ ws,
    float* __restrict__ out) {
  const int b = blockIdx.x >> 3, chunk = blockIdx.x & 7;
  const int tid = threadIdx.x;
  const int e = (chunk << 8) | tid;
  const int* agti = agti_all + b * NN;
  const float* prop = prop_all + (size_t)b * NN * 5;
  unsigned char* W = ws + (size_t)b * IMG_STRIDE;

  if (blockIdx.x == 0 && tid == 0) { out[0] = 0.f; out[1] = 0.f; }
  if (chunk == 0 && tid == 0) *(unsigned*)(W + OFF_OVFC) = 0u;

  __shared__ float sgt[GG * 4];
  __shared__ int cnt4[4];
  sgt[tid] = gtb_all[b * GG * 4 + tid];

  const unsigned short* rp = (const unsigned short*)(W + OFF_RANKP);
  int rank = 0;
  #pragma unroll
  for (int fc = 0; fc < 8; ++fc) rank += rp[(fc << 11) + e];

  const int a = agti[e];
  const float sc = prop[e * 5 + 4];
  const bool pos = a >= 0;

  unsigned long long bal = __ballot(pos);
  if ((tid & 63) == 0) cnt4[tid >> 6] = __popcll(bal);
  __syncthreads();
  if (tid == 0)
    ((unsigned*)(W + OFF_NPOSP))[chunk] =
        (unsigned)(cnt4[0] + cnt4[1] + cnt4[2] + cnt4[3]);

  float4 bx = make_float4(0.f, 0.f, 0.f, 0.f);
  float gi = 0.f, pl = 0.f;
  if (pos) {
    bx = make_float4(prop[e * 5 + 0], prop[e * 5 + 1],
                     prop[e * 5 + 2], prop[e * 5 + 3]);
    gi = iou_pair(sgt[a * 4 + 0], sgt[a * 4 + 1], sgt[a * 4 + 2], sgt[a * 4 + 3],
                  bx.x, bx.y, bx.z, bx.w);
    pl = -logf(fminf(0.5f + fmaxf(gi, EPSF), 1.0f)) * sc;
  }
  ((float4*)(W + OFF_SBOX))[rank] = bx;
  ((float*)(W + OFF_GTPI))[rank] = gi;
  ((float*)(W + OFF_PULL))[rank] = pl;
  ((signed char*)(W + OFF_AGTI))[rank] = (signed char)a;
  ((unsigned*)(W + OFF_CNT))[rank] = 0u;
}

__device__ __forceinline__ int load_npos(const unsigned char* W) {
  const unsigned* np = (const unsigned*)(W + OFF_NPOSP);
  return (int)(np[0] + np[1] + np[2] + np[3] + np[4] + np[5] + np[6] + np[7]);
}

// ------------- kernel 3: tiled all-pairs (sorted) -> in-edge lists ----------
// killer is ALWAYS i (i<j in sorted space). Exact divide-free predicate:
// fl32(inter/denom) > 0.5f  <=>  (double)inter > (0.5+2^-25)*(double)denom
__global__ __launch_bounds__(256) void k_pairs(unsigned char* __restrict__ ws) {
  int bx = blockIdx.x;
  const int b = bx / (NPAIRT * 4);
  int rem = bx % (NPAIRT * 4);
  int p = rem >> 2;
  const int q = rem & 3;
  int r = 0;
  #pragma unroll
  for (int t = 0; t < NTILE; ++t) {
    int wdt = NTILE - t;
    if (p < wdt) { r = t; break; }
    p -= wdt;
  }
  const int c = r + p;
  const int tid = threadIdx.x;
  unsigned char* W = ws + (size_t)b * IMG_STRIDE;
  const float4* box = (const float4*)(W + OFF_SBOX);
  unsigned* cnt = (unsigned*)(W + OFF_CNT);
  unsigned short* inl = (unsigned short*)(W + OFF_INL);
  unsigned* ovfc = (unsigned*)(W + OFF_OVFC);
  unsigned* ovf = (unsigned*)(W + OFF_OVF);
  const int npos = load_npos(W);

  const int jbase = c * TILE + q * CSLICE;
  if (jbase >= npos || r * TILE >= npos) return;   // uniform exits

  __shared__ float4 cbox[CSLICE];
  __shared__ float carea[CSLICE];

  if (tid < CSLICE) {
    float4 Bx = box[jbase + tid];
    cbox[tid] = Bx;
    carea[tid] = (Bx.z - Bx.x) * (Bx.w - Bx.y);
  }
  const int i = r * TILE + tid;
  const float4 A = box[i];
  const float area_a = (A.z - A.x) * (A.w - A.y);
  __syncthreads();

  const double THR = 0.5 + 0x1p-25;
  #pragma unroll 8
  for (int jj = 0; jj < CSLICE; ++jj) {
    float4 Bx = cbox[jj];
    float ab = carea[jj];
    float lx = fmaxf(A.x, Bx.x), ly = fmaxf(A.y, Bx.y);
    float rx = fminf(A.z, Bx.z), ry = fminf(A.w, Bx.w);
    float w = fmaxf(rx - lx, 0.0f), h = fmaxf(ry - ly, 0.0f);
    float inter = w * h;
    float denom = area_a + ab - inter + 1e-10f;   // ((aa+ab)-inter)+eps
    int j = jbase + jj;
    bool hit = ((double)inter > THR * (double)denom) && (j > i) && (j < npos);
    if (hit) {
      unsigned pos = atomicAdd(&cnt[j], 1u);
      if (pos < CAP) {
        inl[j * CAP + pos] = (unsigned short)i;
      } else {
        unsigned o = atomicAdd(ovfc, 1u);
        if (o < OVF_MAX) ovf[o] = ((unsigned)j << 16) | (unsigned)i;
      }
    }
  }
}

// ------------- kernel 4: single-sweep resolve + bookkeeping + final ---------
__global__ __launch_bounds__(512) void k_resolve(
    const float* __restrict__ gtb_all,
    unsigned char* __restrict__ ws,
    float* __restrict__ out) {
  const int b = blockIdx.x, tid = threadIdx.x;
  const int wave = tid >> 6, lane = tid & 63;
  unsigned char* W = ws + (size_t)b * IMG_STRIDE;
  const float4* sbox = (const float4*)(W + OFF_SBOX);
  const float* gtpi = (const float*)(W + OFF_GTPI);
  const float* pull = (const float*)(W + OFF_PULL);
  const signed char* ag8 = (const signed char*)(W + OFF_AGTI);
  const unsigned* cntg = (const unsigned*)(W + OFF_CNT);
  const int npos = load_npos(W);

  __shared__ __align__(8) unsigned short inl_l[NN * CAP];  // 49152 B
  __shared__ unsigned char cnt8[NN];
  __shared__ unsigned long long selw[32];
  __shared__ unsigned l_ovf[OVF_MAX];                      // 8192 B
  __shared__ int minselg[GG], bestposg[GG];
  __shared__ int s_maxsel, s_hasrem;
  __shared__ float wtp[8];

  const unsigned ovfc_raw = *(const unsigned*)(W + OFF_OVFC);
  const int novf = (int)(ovfc_raw < OVF_MAX ? ovfc_raw : OVF_MAX);
  const bool ovflow = ovfc_raw > OVF_MAX;

  if (tid == 0) { s_maxsel = -1; s_hasrem = 0; }
  if (tid < GG) { minselg[tid] = NN; bestposg[tid] = NN; }
  {
    const unsigned long long* src = (const unsigned long long*)(W + OFF_INL);
    unsigned long long* dst = (unsigned long long*)inl_l;
    #pragma unroll
    for (int k = 0; k < 12; ++k) dst[tid + (k << 9)] = src[tid + (k << 9)];
  }
  for (int s = tid; s < NN; s += 512) {
    unsigned cc = cntg[s];
    cnt8[s] = (unsigned char)(cc > 255u ? 255u : cc);
  }
  for (int o = tid; o < novf; o += 512) l_ovf[o] = ((const unsigned*)(W + OFF_OVF))[o];
  __syncthreads();

  // ---- single ordered sweep (wave 0 only): exact sequential-NMS result ----
  if (wave == 0) {
    for (int w = 0; w < 32; ++w) {
      if ((w << 6) >= npos) { if (lane == 0) selw[w] = 0ull; continue; }
      const int e = (w << 6) | lane;
      const bool pos = e < npos;
      unsigned long long intra = 0ull;
      bool ckill = false;
      const int cfull = pos ? cnt8[e] : 0;
      const int ce = cfull < CAP ? cfull : CAP;
      // fixed-trip unroll: all LDS reads issue independently (one wait)
      #pragma unroll
      for (int kk = 0; kk < CAP; ++kk) {
        int idx = inl_l[e * CAP + kk];
        bool valid = kk < ce;
        bool intraw = idx >= (w << 6);
        unsigned long long selbit = (selw[idx >> 6] >> (idx & 63)) & 1ull;
        intra |= (valid && intraw) ? (1ull << (idx & 63)) : 0ull;
        ckill |= (valid && !intraw && selbit != 0ull);
      }
      if (novf && pos && cfull > CAP) {
        for (int o = 0; o < novf; ++o) {
          unsigned pk = l_ovf[o];
          if ((int)(pk >> 16) == e) {
            int idx = (int)(pk & 0xffffu);
            if (idx >= (w << 6)) intra |= 1ull << (idx & 63);
            else ckill |= ((selw[idx >> 6] >> (idx & 63)) & 1ull) != 0ull;
          }
        }
      }
      // ultra-rare exact fallback (overflow list itself overflowed)
      bool fb = ovflow && pos && cfull > CAP;
      if (__any(fb ? 1 : 0)) {
        float4 mb = sbox[e];
        if (fb) {
          ckill = false; intra = 0ull;
          for (int wp = 0; wp < w && !ckill; ++wp) {
            unsigned long long m = selw[wp];
            while (m && !ckill) {
              int bit = __ffsll((long long)m) - 1;
              m &= m - 1ull;
              float4 I = sbox[(wp << 6) | bit];
              if (iou_pair(I.x, I.y, I.z, I.w, mb.x, mb.y, mb.z, mb.w) > 0.5f)
                ckill = true;
            }
          }
        }
        for (int lp = 0; lp < 64; ++lp) {
          float bx1 = __shfl(mb.x, lp, 64), by1 = __shfl(mb.y, lp, 64);
          float bx2 = __shfl(mb.z, lp, 64), by2 = __shfl(mb.w, lp, 64);
          if (fb && lp < lane && ((w << 6) | lp) < npos) {
            if (iou_pair(bx1, by1, bx2, by2, mb.x, mb.y, mb.z, mb.w) > 0.5f)
              intra |= 1ull << lp;
          }
        }
      }
      const bool alive0 = pos && !ckill;
      bool alive = alive0;
      unsigned long long bal = __ballot(alive), prev;
      do {
        prev = bal;
        alive = alive0 && ((intra & bal) == 0ull);
        bal = __ballot(alive);
      } while (bal != prev);
      if (lane == 0) selw[w] = bal;
    }
  }
  __syncthreads();

  // ---- bookkeeping pass 1 ----
  float tp_part = 0.f;
  int maxsel_p = -1;
  #pragma unroll
  for (int k = 0; k < 4; ++k) {
    int e = tid + (k << 9);
    if (e < npos) {
      int g = ag8[e];
      atomicMin(&bestposg[g], e);
      bool sel = (selw[e >> 6] >> (e & 63)) & 1ull;
      if (sel) {
        atomicMin(&minselg[g], e);
        tp_part += pull[e];
        maxsel_p = e > maxsel_p ? e : maxsel_p;
      }
    }
  }
  #pragma unroll
  for (int off = 32; off; off >>= 1) {
    int o = __shfl_xor(maxsel_p, off, 64);
    maxsel_p = o > maxsel_p ? o : maxsel_p;
  }
  if (lane == 0) atomicMax(&s_maxsel, maxsel_p);
  __syncthreads();

  // ---- pass 2: first-of-g subtraction; has_rem for last selection ----
  const int idx_last = s_maxsel;
  #pragma unroll
  for (int k = 0; k < 4; ++k) {
    int e = tid + (k << 9);
    if (e >= npos) continue;
    bool sel = (selw[e >> 6] >> (e & 63)) & 1ull;
    if (sel) {
      if (e == minselg[ag8[e]]) tp_part -= pull[e];   // first of its g
    } else {
      // killed box: active at i_last's turn iff its ONLY selected killer is i_last
      bool other = false;
      int cfull = cnt8[e];
      int ce = cfull < CAP ? cfull : CAP;
      #pragma unroll
      for (int kk = 0; kk < CAP; ++kk) {
        int idx = inl_l[e * CAP + kk];
        bool valid = kk < ce;
        other |= valid && idx != idx_last &&
                 ((selw[idx >> 6] >> (idx & 63)) & 1ull) != 0ull;
      }
      if (!other && novf && cfull > CAP) {
        for (int o = 0; o < novf && !other; ++o) {
          unsigned pk = l_ovf[o];
          if ((int)(pk >> 16) == e) {
            int idx = (int)(pk & 0xffffu);
            if (idx != idx_last && ((selw[idx >> 6] >> (idx & 63)) & 1ull)) other = true;
          }
        }
      }
      if (!other && ovflow && cfull > CAP) {
        float4 mb = sbox[e];
        for (int wp = 0; wp <= ((e - 1) >> 6) && !other; ++wp) {
          unsigned long long m = selw[wp];
          while (m && !other) {
            int bit = __ffsll((long long)m) - 1;
            m &= m - 1ull;
            int idx = (wp << 6) | bit;
            if (idx < e && idx != idx_last) {
              float4 I = sbox[idx];
              if (iou_pair(I.x, I.y, I.z, I.w, mb.x, mb.y, mb.z, mb.w) > 0.5f)
                other = true;
            }
          }
        }
      }
      if (!other) s_hasrem = 1;
    }
  }
  #pragma unroll
  for (int off = 32; off; off >>= 1) tp_part += __shfl_xor(tp_part, off, 64);
  if (lane == 0) wtp[wave] = tp_part;
  __syncthreads();

  // ---- push + finalize (wave 0; lane == g) ----
  if (wave == 0) {
    float mypush = 0.f;
    int mycnt2 = 0;
    int bp = bestposg[lane];
    bool seen = minselg[lane] < NN;
    if (bp < NN) {
      float h = gtb_all[b * GG * 4 + lane * 4 + 3] - gtb_all[b * GG * 4 + lane * 4 + 1];
      if (h >= MIN_H && !seen) { mypush = 1.0f - gtpi[bp]; mycnt2 = 1; }
    }
    #pragma unroll
    for (int off = 32; off; off >>= 1) {
      mypush += __shfl_xor(mypush, off, 64);
      mycnt2 += __shfl_xor(mycnt2, off, 64);
    }
    if (lane == 0) {
      float tp = 0.f;
      #pragma unroll
      for (int w = 0; w < 8; ++w) tp += wtp[w];
      int total_sel = 0;
      for (int w = 0; w < 32; ++w) total_sel += __popcll(selw[w]);
      int distinct = 0;
      for (int g = 0; g < GG; ++g) distinct += (minselg[g] < NN) ? 1 : 0;
      int pc = total_sel - distinct;
      if (idx_last >= 0) {
        int gl = ag8[idx_last];
        // last selection's pull counts only if non-first-of-g AND has_rem
        if (idx_last != minselg[gl] && !s_hasrem) tp -= pull[idx_last];
      }
      float push_loss = 0.f, pull_loss = 0.f;
      if (npos > 1) {
        pull_loss = tp / ((float)pc + EPSF);
        push_loss = mypush / ((float)mycnt2 + EPSF);
      }
      atomicAdd(&out[0], push_loss * (1.0f / B_IMG));
      atomicAdd(&out[1], pull_loss * (1.0f / B_IMG));
    }
  }
}

extern "C" void kernel_launch(void* const* d_in, const int* in_sizes, int n_in,
                              void* d_out, int out_size, void* d_ws, size_t ws_size,
                              hipStream_t stream) {
  const int* agti = (const int*)d_in[1];
  const float* gtb = (const float*)d_in[2];
  const float* prop = (const float*)d_in[3];
  unsigned char* ws = (unsigned char*)d_ws;
  float* out = (float*)d_out;

  k_rank<<<B_IMG * 64, 256, 0, stream>>>(agti, prop, ws);
  k_scatter<<<B_IMG * 8, 256, 0, stream>>>(agti, gtb, prop, ws, out);
  k_pairs<<<B_IMG * NPAIRT * 4, 256, 0, stream>>>(ws);
  k_resolve<<<B_IMG, 512, 0, stream>>>(gtb, ws, out);
}